// Round 8
// baseline (256.012 us; speedup 1.0000x reference)
//
#include <hip/hip_runtime.h>
#include <hip/hip_bf16.h>

#define IN_CH 128
#define HID_CH 64
#define OUT_CH 32
#define EPB 2048  // edges per partition block
#define MAXB 512  // max buckets (N <= 131072)

typedef unsigned short ushort_t;
typedef __attribute__((ext_vector_type(8))) short short8;
typedef __attribute__((ext_vector_type(4))) float float4v;

static __device__ __forceinline__ ushort_t f2bf(float f) {
    unsigned u = __float_as_uint(f);
    unsigned r = (u + 0x7fff + ((u >> 16) & 1)) >> 16;  // RNE
    return (ushort_t)r;
}
static __device__ __forceinline__ float bf_lo(unsigned u) { return __uint_as_float(u << 16); }
static __device__ __forceinline__ float bf_hi(unsigned u) { return __uint_as_float(u & 0xffff0000u); }

// ---------------- radix partition by dst>>8 (+ prepW in 4 trailing blocks) ----------------

__global__ __launch_bounds__(256) void k_partition(const int* __restrict__ src,
                                                   const int* __restrict__ dst,
                                                   int* __restrict__ gcursor,
                                                   unsigned* __restrict__ pairs,
                                                   int E, int nbk, int cap, int PB,
                                                   const float* __restrict__ W1,
                                                   unsigned* __restrict__ wsW) {
    __shared__ int lhist[MAXB];
    __shared__ int lbase[MAXB];
    __shared__ int lcur[MAXB];
    const int tid = threadIdx.x;

    if (blockIdx.x >= PB) {  // prepW blocks: W1 -> b-fragment repack (bf16)
        int s = (blockIdx.x - PB) * 256 + tid;  // 0..1023
        int lane = s & 63;
        int nt = (s >> 6) & 3;
        int kc = s >> 8;
        int c = nt * 16 + (lane & 15);
        int k0 = kc * 32 + (lane >> 4) * 8;
        unsigned o[4];
#pragma unroll
        for (int d = 0; d < 4; ++d) {
            unsigned lo = f2bf(W1[(k0 + 2 * d) * 64 + c]);
            unsigned hi = f2bf(W1[(k0 + 2 * d + 1) * 64 + c]);
            o[d] = lo | (hi << 16);
        }
        ((uint4*)wsW)[s] = make_uint4(o[0], o[1], o[2], o[3]);
        return;
    }

    for (int b = tid; b < nbk; b += 256) { lhist[b] = 0; lcur[b] = 0; }
    __syncthreads();
    int s[8], d[8];
    const int e0 = blockIdx.x * EPB;
#pragma unroll
    for (int j = 0; j < 8; ++j) {
        int e = e0 + j * 256 + tid;
        if (e < E) {
            s[j] = src[e];
            d[j] = dst[e];
            atomicAdd(&lhist[d[j] >> 8], 1);
        } else {
            d[j] = -1;
        }
    }
    __syncthreads();
    for (int b = tid; b < nbk; b += 256)
        lbase[b] = lhist[b] ? atomicAdd(&gcursor[b], lhist[b]) : 0;
    __syncthreads();
#pragma unroll
    for (int j = 0; j < 8; ++j) {
        if (d[j] >= 0) {
            int b = d[j] >> 8;
            int loc = atomicAdd(&lcur[b], 1);
            int idx = lbase[b] + loc;
            if (idx < cap)
                pairs[(long long)b * cap + idx] = ((unsigned)s[j] << 8) | (unsigned)(d[j] & 255);
        }
    }
}

// ---------------- fused per-bucket build (inline bucket-total scan) ----------------
// 1) scan min(gcursor,cap) over 512 entries (2/thread) -> this bucket's base + grand total
// 2) row counts -> LDS scan -> rowptr + dis -> direct col placement

__global__ __launch_bounds__(256) void k_bucket_build(const unsigned* __restrict__ pairs,
                                                      const int* __restrict__ gcursor,
                                                      int* __restrict__ rowptr,
                                                      int* __restrict__ col,
                                                      float* __restrict__ dis,
                                                      int cap, int N) {
    __shared__ int lc[256];
    __shared__ int ls[256];
    __shared__ int lcur[256];
    const int b = blockIdx.x, tid = threadIdx.x;

    // inline exclusive-scan of bucket totals (pairs of entries per thread)
    int ga = min(gcursor[2 * tid], cap);
    int gb = min(gcursor[2 * tid + 1], cap);
    ls[tid] = ga + gb;
    __syncthreads();
    for (int off = 1; off < 256; off <<= 1) {
        int val = (tid >= off) ? ls[tid - off] : 0;
        __syncthreads();
        ls[tid] += val;
        __syncthreads();
    }
    const int p = b >> 1;
    const int base = (p ? ls[p - 1] : 0) + ((b & 1) ? min(gcursor[b - 1], cap) : 0);
    const int total = ls[255];
    __syncthreads();
    if (b == 0 && tid == 0) rowptr[N] = total;

    lc[tid] = 0;
    __syncthreads();
    const int cnt = min(gcursor[b], cap);
    const unsigned* pp = pairs + (long long)b * cap;
    for (int i = tid; i < cnt; i += 256) atomicAdd(&lc[pp[i] & 255], 1);
    __syncthreads();
    const int v = lc[tid];
    ls[tid] = v;
    __syncthreads();
    for (int off = 1; off < 256; off <<= 1) {
        int val = (tid >= off) ? ls[tid - off] : 0;
        __syncthreads();
        ls[tid] += val;
        __syncthreads();
    }
    const int excl = ls[tid] - v;
    const int row = b * 256 + tid;
    if (row < N) {
        rowptr[row] = base + excl;
        dis[row] = rsqrtf((float)(v + 1));  // +1 self-loop
    }
    lcur[tid] = base + excl;
    __syncthreads();
    for (int i = tid; i < cnt; i += 256) {
        unsigned pk = pp[i];
        int pos = atomicAdd(&lcur[pk & 255], 1);
        col[pos] = (int)(pk >> 8);
    }
}

// ---------------- L1 matmul via MFMA ----------------

__global__ __launch_bounds__(256) void k_mm1(const float* __restrict__ X,
                                             const unsigned* __restrict__ wsW,
                                             ushort_t* __restrict__ H, int N) {
    const int tid = threadIdx.x;
    const int wv = tid >> 6, lane = tid & 63;
    const int quad = lane >> 4, n16 = lane & 15;
    const int rowbase = blockIdx.x * 64 + wv * 16;
    const int myrow = rowbase + n16;
    const bool rok = (myrow < N);

    float4v acc0 = {}, acc1 = {}, acc2 = {}, acc3 = {};

#pragma unroll
    for (int kc = 0; kc < 4; ++kc) {
        float4 xa = make_float4(0.f, 0.f, 0.f, 0.f), xb = xa;
        if (rok) {
            const float4* p = (const float4*)(X + (long long)myrow * 128 + kc * 32 + quad * 8);
            xa = p[0];
            xb = p[1];
        }
        unsigned pk[4];
        pk[0] = (unsigned)f2bf(xa.x) | ((unsigned)f2bf(xa.y) << 16);
        pk[1] = (unsigned)f2bf(xa.z) | ((unsigned)f2bf(xa.w) << 16);
        pk[2] = (unsigned)f2bf(xb.x) | ((unsigned)f2bf(xb.y) << 16);
        pk[3] = (unsigned)f2bf(xb.z) | ((unsigned)f2bf(xb.w) << 16);
        short8 a;
        a[0] = (short)(pk[0] & 0xffff); a[1] = (short)(pk[0] >> 16);
        a[2] = (short)(pk[1] & 0xffff); a[3] = (short)(pk[1] >> 16);
        a[4] = (short)(pk[2] & 0xffff); a[5] = (short)(pk[2] >> 16);
        a[6] = (short)(pk[3] & 0xffff); a[7] = (short)(pk[3] >> 16);

        const short8* wb = (const short8*)wsW;
        short8 b0 = wb[(kc * 4 + 0) * 64 + lane];
        short8 b1 = wb[(kc * 4 + 1) * 64 + lane];
        short8 b2 = wb[(kc * 4 + 2) * 64 + lane];
        short8 b3 = wb[(kc * 4 + 3) * 64 + lane];

        acc0 = __builtin_amdgcn_mfma_f32_16x16x32_bf16(a, b0, acc0, 0, 0, 0);
        acc1 = __builtin_amdgcn_mfma_f32_16x16x32_bf16(a, b1, acc1, 0, 0, 0);
        acc2 = __builtin_amdgcn_mfma_f32_16x16x32_bf16(a, b2, acc2, 0, 0, 0);
        acc3 = __builtin_amdgcn_mfma_f32_16x16x32_bf16(a, b3, acc3, 0, 0, 0);
    }

#pragma unroll
    for (int i = 0; i < 4; ++i) {
        int row = rowbase + quad * 4 + i;
        if (row < N) {
            long long o = (long long)row * 64 + n16;
            H[o]      = f2bf(acc0[i]);
            H[o + 16] = f2bf(acc1[i]);
            H[o + 32] = f2bf(acc2[i]);
            H[o + 48] = f2bf(acc3[i]);
        }
    }
}

// ---------------- fused agg64 + mm2, 2 rows per wave-iteration ----------------
// h2 = relu(b1 + D A D h1) @ W2 ; z never materialized. 16 gathers in flight/lane.

__global__ __launch_bounds__(256) void k_agg64_mm2(const unsigned* __restrict__ h,
                                                   const int* __restrict__ rowptr,
                                                   const int* __restrict__ col,
                                                   const float* __restrict__ dis,
                                                   const float* __restrict__ b1,
                                                   const float* __restrict__ W2,
                                                   unsigned* __restrict__ h2, int N) {
    __shared__ float zbuf[4][2][64];
    const int wv = threadIdx.x >> 6, lane = threadIdx.x & 63;
    const int t = lane & 31, g = lane >> 5;  // channel-pair t, edge-group / k-half g

    float w[32];  // W2 slice: w[k] = W2[(g*32+k)*32 + t]
#pragma unroll
    for (int k = 0; k < 32; ++k) w[k] = W2[(g * 32 + k) * 32 + t];
    const float2 bv = ((const float2*)b1)[t];

    const int wave0 = blockIdx.x * 4 + wv;
    const int nwaves = gridDim.x * 4;

    for (int r0 = wave0 * 2; r0 < N; r0 += nwaves * 2) {
        const int r1 = r0, r2 = r0 + 1;
        const bool has2 = (r2 < N);
        const int start1 = rowptr[r1];
        const int deg1 = rowptr[r1 + 1] - start1;
        int start2 = start1, deg2 = 0;
        if (has2) { start2 = rowptr[r2]; deg2 = rowptr[r2 + 1] - start2; }
        const float dr1 = dis[r1];
        const float dr2 = has2 ? dis[r2] : 0.f;

        int c1 = r1, c2 = r1;
        float e1 = 0.f, e2 = 0.f;
        if (lane < deg1) { c1 = col[start1 + lane]; e1 = dis[c1]; }
        if (lane < deg2) { c2 = col[start2 + lane]; e2 = dis[c2]; }

        unsigned us1 = h[r1 * 32 + t];
        unsigned us2 = h[(has2 ? r2 : r1) * 32 + t];
        float w01 = g ? 0.f : dr1, w02 = g ? 0.f : dr2;
        float ax1 = w01 * bf_lo(us1), ay1 = w01 * bf_hi(us1);
        float ax2 = w02 * bf_lo(us2), ay2 = w02 * bf_hi(us2);

        const int cntm = min(max(deg1, deg2), 64);
        for (int k0 = 0; k0 < cntm; k0 += 16) {  // 16 independent gathers/lane/iter
#pragma unroll
            for (int u = 0; u < 8; ++u) {
                int slot = k0 + 2 * u + g;
                int s1 = __shfl(c1, slot);
                float f1 = __shfl(e1, slot);
                int s2 = __shfl(c2, slot);
                float f2 = __shfl(e2, slot);
                unsigned u1 = h[s1 * 32 + t];
                unsigned u2 = h[s2 * 32 + t];
                ax1 += f1 * bf_lo(u1); ay1 += f1 * bf_hi(u1);
                ax2 += f2 * bf_lo(u2); ay2 += f2 * bf_hi(u2);
            }
        }
        for (int j = start1 + 64 + g; j < start1 + deg1; j += 2) {  // rare tails
            int s = col[j];
            float f = dis[s];
            unsigned uu = h[s * 32 + t];
            ax1 += f * bf_lo(uu); ay1 += f * bf_hi(uu);
        }
        for (int j = start2 + 64 + g; j < start2 + deg2; j += 2) {
            int s = col[j];
            float f = dis[s];
            unsigned uu = h[s * 32 + t];
            ax2 += f * bf_lo(uu); ay2 += f * bf_hi(uu);
        }
        ax1 += __shfl_down(ax1, 32); ay1 += __shfl_down(ay1, 32);
        ax2 += __shfl_down(ax2, 32); ay2 += __shfl_down(ay2, 32);

        if (!g) {
            float2 z1v, z2v;
            z1v.x = bv.x + dr1 * ax1; z1v.y = bv.y + dr1 * ay1;
            z2v.x = bv.x + dr2 * ax2; z2v.y = bv.y + dr2 * ay2;
            *(float2*)&zbuf[wv][0][2 * t] = z1v;
            *(float2*)&zbuf[wv][1][2 * t] = z2v;
        }
        __builtin_amdgcn_wave_barrier();

        float a1 = 0.f, a2 = 0.f;
        const float* zp1 = &zbuf[wv][0][g * 32];
        const float* zp2 = &zbuf[wv][1][g * 32];
#pragma unroll
        for (int k = 0; k < 32; k += 4) {
            float4 zv = *(const float4*)(zp1 + k);
            a1 += fmaxf(zv.x, 0.f) * w[k] + fmaxf(zv.y, 0.f) * w[k + 1] +
                  fmaxf(zv.z, 0.f) * w[k + 2] + fmaxf(zv.w, 0.f) * w[k + 3];
            float4 zw = *(const float4*)(zp2 + k);
            a2 += fmaxf(zw.x, 0.f) * w[k] + fmaxf(zw.y, 0.f) * w[k + 1] +
                  fmaxf(zw.z, 0.f) * w[k + 2] + fmaxf(zw.w, 0.f) * w[k + 3];
        }
        __builtin_amdgcn_wave_barrier();
        a1 += __shfl_down(a1, 32);  // lane c<32: out channel c
        a2 += __shfl_down(a2, 32);

        const int tt = lane & 15;
        float o0 = __shfl(a1, 2 * tt), o1 = __shfl(a1, 2 * tt + 1);
        float p0 = __shfl(a2, 2 * tt), p1 = __shfl(a2, 2 * tt + 1);
        if (lane < 16)
            h2[r1 * 16 + lane] = (unsigned)f2bf(o0) | ((unsigned)f2bf(o1) << 16);
        else if (lane < 32 && has2)
            h2[r2 * 16 + tt] = (unsigned)f2bf(p0) | ((unsigned)f2bf(p1) << 16);
    }
}

// ---------------- agg32: final aggregation, 2 rows per wave (fp32 out) ----------------

__global__ __launch_bounds__(256) void k_agg32(const unsigned* __restrict__ h,
                                               const int* __restrict__ rowptr,
                                               const int* __restrict__ col,
                                               const float* __restrict__ dis,
                                               const float* __restrict__ b,
                                               float* __restrict__ out, int N) {
    const int wave = (blockIdx.x * 256 + threadIdx.x) >> 6;
    const int lane = threadIdx.x & 63;
    const int r1 = 2 * wave, r2 = r1 + 1;
    if (r1 >= N) return;
    const bool has2 = (r2 < N);
    const int t = lane & 15, g = lane >> 4;

    const int start1 = rowptr[r1];
    const int deg1 = rowptr[r1 + 1] - start1;
    int start2 = start1, deg2 = 0;
    if (has2) { start2 = rowptr[r2]; deg2 = rowptr[r2 + 1] - start2; }
    const float dr1 = dis[r1];
    const float dr2 = has2 ? dis[r2] : 0.f;

    int c1 = r1, c2 = r1;
    float e1 = 0.f, e2 = 0.f;
    if (lane < deg1) { c1 = col[start1 + lane]; e1 = dis[c1]; }
    if (lane < deg2) { c2 = col[start2 + lane]; e2 = dis[c2]; }

    unsigned us1 = h[r1 * 16 + t];
    unsigned us2 = h[(has2 ? r2 : r1) * 16 + t];
    float w01 = (g == 0) ? dr1 : 0.f, w02 = (g == 0) ? dr2 : 0.f;
    float ax1 = w01 * bf_lo(us1), ay1 = w01 * bf_hi(us1);
    float ax2 = w02 * bf_lo(us2), ay2 = w02 * bf_hi(us2);

    const int cntm = min(max(deg1, deg2), 64);
    for (int k0 = 0; k0 < cntm; k0 += 32) {  // 16 independent gathers/lane/iter
#pragma unroll
        for (int u = 0; u < 8; ++u) {
            int slot = k0 + 4 * u + g;
            int s1 = __shfl(c1, slot);
            float f1 = __shfl(e1, slot);
            int s2 = __shfl(c2, slot);
            float f2 = __shfl(e2, slot);
            unsigned u1 = h[s1 * 16 + t];
            unsigned u2 = h[s2 * 16 + t];
            ax1 += f1 * bf_lo(u1); ay1 += f1 * bf_hi(u1);
            ax2 += f2 * bf_lo(u2); ay2 += f2 * bf_hi(u2);
        }
    }
    for (int j = start1 + 64 + g; j < start1 + deg1; j += 4) {  // rare tails
        int s = col[j];
        float f = dis[s];
        unsigned uu = h[s * 16 + t];
        ax1 += f * bf_lo(uu); ay1 += f * bf_hi(uu);
    }
    for (int j = start2 + 64 + g; j < start2 + deg2; j += 4) {
        int s = col[j];
        float f = dis[s];
        unsigned uu = h[s * 16 + t];
        ax2 += f * bf_lo(uu); ay2 += f * bf_hi(uu);
    }
    ax1 += __shfl_down(ax1, 32); ay1 += __shfl_down(ay1, 32);
    ax1 += __shfl_down(ax1, 16); ay1 += __shfl_down(ay1, 16);
    ax2 += __shfl_down(ax2, 32); ay2 += __shfl_down(ay2, 32);
    ax2 += __shfl_down(ax2, 16); ay2 += __shfl_down(ay2, 16);

    // row2 results live in lanes 0..15; fetch via shfl for lanes 16..31
    float bx2 = __shfl(ax2, t), by2 = __shfl(ay2, t);
    const float2 bv = ((const float2*)b)[t];
    if (g == 0) {
        float2 o;
        o.x = bv.x + dr1 * ax1;
        o.y = bv.y + dr1 * ay1;
        ((float2*)out)[(long long)r1 * 16 + t] = o;
    } else if (g == 1 && has2) {
        float2 o;
        o.x = bv.x + dr2 * bx2;
        o.y = bv.y + dr2 * by2;
        ((float2*)out)[(long long)r2 * 16 + t] = o;
    }
}

extern "C" void kernel_launch(void* const* d_in, const int* in_sizes, int n_in,
                              void* d_out, int out_size, void* d_ws, size_t ws_size,
                              hipStream_t stream) {
    const float* x  = (const float*)d_in[0];
    const int*   ei = (const int*)d_in[1];
    const float* W1 = (const float*)d_in[2];
    const float* b1 = (const float*)d_in[3];
    const float* W2 = (const float*)d_in[4];
    const float* b2 = (const float*)d_in[5];
    float* out = (float*)d_out;

    const int N = in_sizes[0] / IN_CH;
    const int E = in_sizes[1] / 2;
    const int* esrc = ei;
    const int* edst = ei + E;

    int nbk = (N + 255) >> 8;
    if (nbk > MAXB) nbk = MAXB;
    const int per_b = (E + nbk - 1) / nbk;
    const int cap = per_b + per_b / 4 + 256;  // ~20-sigma headroom

    // workspace layout (4-byte units, regions padded to 16)
    int* rowptr   = (int*)d_ws;                          // N+1
    int* gcursor  = rowptr + (((N + 1) + 15) & ~15);     // MAXB
    unsigned* wsW = (unsigned*)(gcursor + MAXB);         // 4096 dwords (b-frag repack)
    int* col      = (int*)(wsW + 4096);                  // E
    float* dis    = (float*)(col + ((E + 15) & ~15));    // N
    ushort_t* h1  = (ushort_t*)(dis + ((N + 15) & ~15)); // N*64 bf16
    unsigned* scratch = (unsigned*)(h1 + (((long long)N * 64 + 31) & ~31LL));
    unsigned* pairs = scratch;        // nbk*cap dwords (~8.4MB), dead after bucket_build
    unsigned* h2    = scratch;        // N*16 dwords (6.4MB) bf16x2, written after pairs dead

    const int B = 256;
    const int PB = (E + EPB - 1) / EPB;

    hipMemsetAsync(gcursor, 0, MAXB * sizeof(int), stream);
    k_partition<<<PB + 4, B, 0, stream>>>(esrc, edst, gcursor, pairs, E, nbk, cap, PB, W1, wsW);
    k_bucket_build<<<nbk, B, 0, stream>>>(pairs, gcursor, rowptr, col, dis, cap, N);

    k_mm1<<<(N + 63) / 64, B, 0, stream>>>(x, wsW, h1, N);

    // fused layer-1 aggregation + layer-2 transform (2 rows per wave-iter, ~8 rows/wave)
    const int fblocks = (N + 31) / 32;
    k_agg64_mm2<<<fblocks, B, 0, stream>>>((const unsigned*)h1, rowptr, col, dis, b1, W2, h2, N);

    // final aggregation: 2 rows per wave
    const long long waves32 = (N + 1) / 2;
    k_agg32<<<(int)((waves32 * 64 + B - 1) / B), B, 0, stream>>>((const unsigned*)h2, rowptr, col, dis, b2, out, N);
}

// Round 9
// 249.169 us; speedup vs baseline: 1.0275x; 1.0275x over previous
//
#include <hip/hip_runtime.h>
#include <hip/hip_bf16.h>

#define IN_CH 128
#define HID_CH 64
#define OUT_CH 32
#define EPB 2048  // edges per partition block
#define MAXB 512  // max buckets (N <= 131072)

typedef unsigned short ushort_t;
typedef __attribute__((ext_vector_type(8))) short short8;
typedef __attribute__((ext_vector_type(4))) float float4v;

static __device__ __forceinline__ ushort_t f2bf(float f) {
    unsigned u = __float_as_uint(f);
    unsigned r = (u + 0x7fff + ((u >> 16) & 1)) >> 16;  // RNE
    return (ushort_t)r;
}
static __device__ __forceinline__ float bf_lo(unsigned u) { return __uint_as_float(u << 16); }
static __device__ __forceinline__ float bf_hi(unsigned u) { return __uint_as_float(u & 0xffff0000u); }

// ---------------- radix partition by dst>>8 (+ prepW in 4 trailing blocks) ----------------

__global__ __launch_bounds__(256) void k_partition(const int* __restrict__ src,
                                                   const int* __restrict__ dst,
                                                   int* __restrict__ gcursor,
                                                   unsigned* __restrict__ pairs,
                                                   int E, int nbk, int cap, int PB,
                                                   const float* __restrict__ W1,
                                                   unsigned* __restrict__ wsW) {
    __shared__ int lhist[MAXB];
    __shared__ int lbase[MAXB];
    __shared__ int lcur[MAXB];
    const int tid = threadIdx.x;

    if (blockIdx.x >= PB) {  // prepW blocks: W1 -> b-fragment repack (bf16)
        int s = (blockIdx.x - PB) * 256 + tid;  // 0..1023
        int lane = s & 63;
        int nt = (s >> 6) & 3;
        int kc = s >> 8;
        int c = nt * 16 + (lane & 15);
        int k0 = kc * 32 + (lane >> 4) * 8;
        unsigned o[4];
#pragma unroll
        for (int d = 0; d < 4; ++d) {
            unsigned lo = f2bf(W1[(k0 + 2 * d) * 64 + c]);
            unsigned hi = f2bf(W1[(k0 + 2 * d + 1) * 64 + c]);
            o[d] = lo | (hi << 16);
        }
        ((uint4*)wsW)[s] = make_uint4(o[0], o[1], o[2], o[3]);
        return;
    }

    for (int b = tid; b < nbk; b += 256) { lhist[b] = 0; lcur[b] = 0; }
    __syncthreads();
    int s[8], d[8];
    const int e0 = blockIdx.x * EPB;
#pragma unroll
    for (int j = 0; j < 8; ++j) {
        int e = e0 + j * 256 + tid;
        if (e < E) {
            s[j] = src[e];
            d[j] = dst[e];
            atomicAdd(&lhist[d[j] >> 8], 1);
        } else {
            d[j] = -1;
        }
    }
    __syncthreads();
    for (int b = tid; b < nbk; b += 256)
        lbase[b] = lhist[b] ? atomicAdd(&gcursor[b], lhist[b]) : 0;
    __syncthreads();
#pragma unroll
    for (int j = 0; j < 8; ++j) {
        if (d[j] >= 0) {
            int b = d[j] >> 8;
            int loc = atomicAdd(&lcur[b], 1);
            int idx = lbase[b] + loc;
            if (idx < cap)
                pairs[(long long)b * cap + idx] = ((unsigned)s[j] << 8) | (unsigned)(d[j] & 255);
        }
    }
}

// ---------------- fused per-bucket build (inline bucket-total scan) ----------------

__global__ __launch_bounds__(256) void k_bucket_build(const unsigned* __restrict__ pairs,
                                                      const int* __restrict__ gcursor,
                                                      int* __restrict__ rowptr,
                                                      int* __restrict__ col,
                                                      float* __restrict__ dis,
                                                      int cap, int N) {
    __shared__ int lc[256];
    __shared__ int ls[256];
    __shared__ int lcur[256];
    const int b = blockIdx.x, tid = threadIdx.x;

    // inline exclusive-scan of bucket totals (pairs of entries per thread)
    int ga = min(gcursor[2 * tid], cap);
    int gb = min(gcursor[2 * tid + 1], cap);
    ls[tid] = ga + gb;
    __syncthreads();
    for (int off = 1; off < 256; off <<= 1) {
        int val = (tid >= off) ? ls[tid - off] : 0;
        __syncthreads();
        ls[tid] += val;
        __syncthreads();
    }
    const int p = b >> 1;
    const int base = (p ? ls[p - 1] : 0) + ((b & 1) ? min(gcursor[b - 1], cap) : 0);
    const int total = ls[255];
    __syncthreads();
    if (b == 0 && tid == 0) rowptr[N] = total;

    lc[tid] = 0;
    __syncthreads();
    const int cnt = min(gcursor[b], cap);
    const unsigned* pp = pairs + (long long)b * cap;
    for (int i = tid; i < cnt; i += 256) atomicAdd(&lc[pp[i] & 255], 1);
    __syncthreads();
    const int v = lc[tid];
    ls[tid] = v;
    __syncthreads();
    for (int off = 1; off < 256; off <<= 1) {
        int val = (tid >= off) ? ls[tid - off] : 0;
        __syncthreads();
        ls[tid] += val;
        __syncthreads();
    }
    const int excl = ls[tid] - v;
    const int row = b * 256 + tid;
    if (row < N) {
        rowptr[row] = base + excl;
        dis[row] = rsqrtf((float)(v + 1));  // +1 self-loop
    }
    lcur[tid] = base + excl;
    __syncthreads();
    for (int i = tid; i < cnt; i += 256) {
        unsigned pk = pp[i];
        int pos = atomicAdd(&lcur[pk & 255], 1);
        col[pos] = (int)(pk >> 8);
    }
}

// ---------------- L1 matmul via MFMA ----------------

__global__ __launch_bounds__(256) void k_mm1(const float* __restrict__ X,
                                             const unsigned* __restrict__ wsW,
                                             ushort_t* __restrict__ H, int N) {
    const int tid = threadIdx.x;
    const int wv = tid >> 6, lane = tid & 63;
    const int quad = lane >> 4, n16 = lane & 15;
    const int rowbase = blockIdx.x * 64 + wv * 16;
    const int myrow = rowbase + n16;
    const bool rok = (myrow < N);

    float4v acc0 = {}, acc1 = {}, acc2 = {}, acc3 = {};

#pragma unroll
    for (int kc = 0; kc < 4; ++kc) {
        float4 xa = make_float4(0.f, 0.f, 0.f, 0.f), xb = xa;
        if (rok) {
            const float4* p = (const float4*)(X + (long long)myrow * 128 + kc * 32 + quad * 8);
            xa = p[0];
            xb = p[1];
        }
        unsigned pk[4];
        pk[0] = (unsigned)f2bf(xa.x) | ((unsigned)f2bf(xa.y) << 16);
        pk[1] = (unsigned)f2bf(xa.z) | ((unsigned)f2bf(xa.w) << 16);
        pk[2] = (unsigned)f2bf(xb.x) | ((unsigned)f2bf(xb.y) << 16);
        pk[3] = (unsigned)f2bf(xb.z) | ((unsigned)f2bf(xb.w) << 16);
        short8 a;
        a[0] = (short)(pk[0] & 0xffff); a[1] = (short)(pk[0] >> 16);
        a[2] = (short)(pk[1] & 0xffff); a[3] = (short)(pk[1] >> 16);
        a[4] = (short)(pk[2] & 0xffff); a[5] = (short)(pk[2] >> 16);
        a[6] = (short)(pk[3] & 0xffff); a[7] = (short)(pk[3] >> 16);

        const short8* wb = (const short8*)wsW;
        short8 b0 = wb[(kc * 4 + 0) * 64 + lane];
        short8 b1 = wb[(kc * 4 + 1) * 64 + lane];
        short8 b2 = wb[(kc * 4 + 2) * 64 + lane];
        short8 b3 = wb[(kc * 4 + 3) * 64 + lane];

        acc0 = __builtin_amdgcn_mfma_f32_16x16x32_bf16(a, b0, acc0, 0, 0, 0);
        acc1 = __builtin_amdgcn_mfma_f32_16x16x32_bf16(a, b1, acc1, 0, 0, 0);
        acc2 = __builtin_amdgcn_mfma_f32_16x16x32_bf16(a, b2, acc2, 0, 0, 0);
        acc3 = __builtin_amdgcn_mfma_f32_16x16x32_bf16(a, b3, acc3, 0, 0, 0);
    }

#pragma unroll
    for (int i = 0; i < 4; ++i) {
        int row = rowbase + quad * 4 + i;
        if (row < N) {
            long long o = (long long)row * 64 + n16;
            H[o]      = f2bf(acc0[i]);
            H[o + 16] = f2bf(acc1[i]);
            H[o + 32] = f2bf(acc2[i]);
            H[o + 48] = f2bf(acc3[i]);
        }
    }
}

// ---------------- fused agg64 + mm2: 16-lane edge groups, uint2 gathers ----------------
// h2 = relu(b1 + D(A+I)D h1) @ W2 ; z never materialized; W2 in LDS (frees VGPRs).
// Lane layout (gather): t = lane&15 covers channels 4t..4t+3 (one uint2 = 8B);
// g = lane>>4 in 0..3 = edge group. 4 uint2 loads/lane in flight (16 edges/wave).

__global__ __launch_bounds__(256) void k_agg64_mm2(const unsigned* __restrict__ h,
                                                   const int* __restrict__ rowptr,
                                                   const int* __restrict__ col,
                                                   const float* __restrict__ dis,
                                                   const float* __restrict__ b1,
                                                   const float* __restrict__ W2,
                                                   unsigned* __restrict__ h2, int N) {
    __shared__ float zbuf[4][64];
    __shared__ float sW2[64 * 32];  // 8 KB
    const int tid = threadIdx.x;
    for (int i = tid; i < 512; i += 256) ((float4*)sW2)[i] = ((const float4*)W2)[i];
    __syncthreads();

    const int wv = tid >> 6, lane = tid & 63;
    const int t = lane & 15, g = lane >> 4;      // gather mapping
    const int c32 = lane & 31, kh = lane >> 5;   // dot mapping: out-ch c32, k-half kh
    const float4 bq = ((const float4*)b1)[t];    // b1 channels 4t..4t+3

    const int wave0 = blockIdx.x * 4 + wv;
    const int nwaves = gridDim.x * 4;
    const uint2* h2w = (const uint2*)h;

    for (int row = wave0; row < N; row += nwaves) {
        const int start = rowptr[row];
        const int deg = rowptr[row + 1] - start;
        const float dr = dis[row];

        int myCol = row;
        float myDis = 0.f;
        if (lane < deg) {
            myCol = col[start + lane];
            myDis = dis[myCol];
        }

        uint2 us = h2w[row * 16 + t];  // self-loop (group 0 only)
        float w0 = (g == 0) ? dr : 0.f;
        float a0 = w0 * bf_lo(us.x), a1 = w0 * bf_hi(us.x);
        float a2 = w0 * bf_lo(us.y), a3 = w0 * bf_hi(us.y);

        const int cnt = min(deg, 64);
        for (int k0 = 0; k0 < cnt; k0 += 16) {  // 16 edges per iter, 4 uint2/lane in flight
#pragma unroll
            for (int u = 0; u < 4; ++u) {
                int slot = k0 + 4 * u + g;
                int s = __shfl(myCol, slot);
                float f = __shfl(myDis, slot);
                uint2 uu = h2w[s * 16 + t];
                a0 += f * bf_lo(uu.x); a1 += f * bf_hi(uu.x);
                a2 += f * bf_lo(uu.y); a3 += f * bf_hi(uu.y);
            }
        }
        for (int j = start + 64 + g; j < start + deg; j += 4) {  // rare tail
            int s = col[j];
            float f = dis[s];
            uint2 uu = h2w[s * 16 + t];
            a0 += f * bf_lo(uu.x); a1 += f * bf_hi(uu.x);
            a2 += f * bf_lo(uu.y); a3 += f * bf_hi(uu.y);
        }
        a0 += __shfl_down(a0, 32); a1 += __shfl_down(a1, 32);
        a2 += __shfl_down(a2, 32); a3 += __shfl_down(a3, 32);
        a0 += __shfl_down(a0, 16); a1 += __shfl_down(a1, 16);
        a2 += __shfl_down(a2, 16); a3 += __shfl_down(a3, 16);

        if (lane < 16) {  // lanes 0..15 hold channels 4t..4t+3 totals
            float4 zq;
            zq.x = bq.x + dr * a0;
            zq.y = bq.y + dr * a1;
            zq.z = bq.z + dr * a2;
            zq.w = bq.w + dr * a3;
            *(float4*)&zbuf[wv][4 * t] = zq;
        }
        __builtin_amdgcn_wave_barrier();

        // dot: lane (c32, kh) -> partial over k in [kh*32, kh*32+32)
        float acc = 0.f;
        const float* zp = &zbuf[wv][kh * 32];
        const float* wp = &sW2[kh * 32 * 32 + c32];
#pragma unroll
        for (int k = 0; k < 32; k += 4) {
            float4 zv = *(const float4*)(zp + k);
            acc += fmaxf(zv.x, 0.f) * wp[k * 32] + fmaxf(zv.y, 0.f) * wp[(k + 1) * 32] +
                   fmaxf(zv.z, 0.f) * wp[(k + 2) * 32] + fmaxf(zv.w, 0.f) * wp[(k + 3) * 32];
        }
        __builtin_amdgcn_wave_barrier();
        acc += __shfl_down(acc, 32);  // lanes 0..31 hold out channel c32

        const int tt = lane & 15;
        float o0 = __shfl(acc, 2 * tt);
        float o1 = __shfl(acc, 2 * tt + 1);
        if (lane < 16)
            h2[row * 16 + tt] = (unsigned)f2bf(o0) | ((unsigned)f2bf(o1) << 16);
    }
}

// ---------------- agg32: 8-lane edge groups, uint2 gathers (fp32 out) ----------------
// t = lane&7 covers channels 4t..4t+3; g = lane>>3 in 0..7 = edge group.

__global__ __launch_bounds__(256) void k_agg32(const unsigned* __restrict__ h,
                                               const int* __restrict__ rowptr,
                                               const int* __restrict__ col,
                                               const float* __restrict__ dis,
                                               const float* __restrict__ b,
                                               float* __restrict__ out, int N) {
    const int wave = (blockIdx.x * 256 + threadIdx.x) >> 6;
    const int lane = threadIdx.x & 63;
    if (wave >= N) return;
    const int row = wave;
    const int t = lane & 7, g = lane >> 3;

    const int start = rowptr[row];
    const int deg = rowptr[row + 1] - start;
    const float dr = dis[row];

    int myCol = row;
    float myDis = 0.f;
    if (lane < deg) {
        myCol = col[start + lane];
        myDis = dis[myCol];
    }

    const uint2* hw = (const uint2*)h;
    uint2 us = hw[row * 8 + t];
    float w0 = (g == 0) ? dr : 0.f;
    float a0 = w0 * bf_lo(us.x), a1 = w0 * bf_hi(us.x);
    float a2 = w0 * bf_lo(us.y), a3 = w0 * bf_hi(us.y);

    const int cnt = min(deg, 64);
    for (int k0 = 0; k0 < cnt; k0 += 32) {  // 32 edges per iter, 4 uint2/lane in flight
#pragma unroll
        for (int u = 0; u < 4; ++u) {
            int slot = k0 + 8 * u + g;
            int s = __shfl(myCol, slot);
            float f = __shfl(myDis, slot);
            uint2 uu = hw[s * 8 + t];
            a0 += f * bf_lo(uu.x); a1 += f * bf_hi(uu.x);
            a2 += f * bf_lo(uu.y); a3 += f * bf_hi(uu.y);
        }
    }
    for (int j = start + 64 + g; j < start + deg; j += 8) {  // rare tail
        int s = col[j];
        float f = dis[s];
        uint2 uu = hw[s * 8 + t];
        a0 += f * bf_lo(uu.x); a1 += f * bf_hi(uu.x);
        a2 += f * bf_lo(uu.y); a3 += f * bf_hi(uu.y);
    }
    a0 += __shfl_down(a0, 32); a1 += __shfl_down(a1, 32);
    a2 += __shfl_down(a2, 32); a3 += __shfl_down(a3, 32);
    a0 += __shfl_down(a0, 16); a1 += __shfl_down(a1, 16);
    a2 += __shfl_down(a2, 16); a3 += __shfl_down(a3, 16);
    a0 += __shfl_down(a0, 8);  a1 += __shfl_down(a1, 8);
    a2 += __shfl_down(a2, 8);  a3 += __shfl_down(a3, 8);

    if (lane < 8) {  // lanes 0..7 hold channels 4t..4t+3
        float4 bq = ((const float4*)b)[t];
        float4 o;
        o.x = bq.x + dr * a0;
        o.y = bq.y + dr * a1;
        o.z = bq.z + dr * a2;
        o.w = bq.w + dr * a3;
        ((float4*)out)[(long long)row * 8 + t] = o;
    }
}

extern "C" void kernel_launch(void* const* d_in, const int* in_sizes, int n_in,
                              void* d_out, int out_size, void* d_ws, size_t ws_size,
                              hipStream_t stream) {
    const float* x  = (const float*)d_in[0];
    const int*   ei = (const int*)d_in[1];
    const float* W1 = (const float*)d_in[2];
    const float* b1 = (const float*)d_in[3];
    const float* W2 = (const float*)d_in[4];
    const float* b2 = (const float*)d_in[5];
    float* out = (float*)d_out;

    const int N = in_sizes[0] / IN_CH;
    const int E = in_sizes[1] / 2;
    const int* esrc = ei;
    const int* edst = ei + E;

    int nbk = (N + 255) >> 8;
    if (nbk > MAXB) nbk = MAXB;
    const int per_b = (E + nbk - 1) / nbk;
    const int cap = per_b + per_b / 4 + 256;  // ~20-sigma headroom

    // workspace layout (4-byte units, regions padded to 16)
    int* rowptr   = (int*)d_ws;                          // N+1
    int* gcursor  = rowptr + (((N + 1) + 15) & ~15);     // MAXB
    unsigned* wsW = (unsigned*)(gcursor + MAXB);         // 4096 dwords (b-frag repack)
    int* col      = (int*)(wsW + 4096);                  // E
    float* dis    = (float*)(col + ((E + 15) & ~15));    // N
    ushort_t* h1  = (ushort_t*)(dis + ((N + 15) & ~15)); // N*64 bf16
    unsigned* scratch = (unsigned*)(h1 + (((long long)N * 64 + 31) & ~31LL));
    unsigned* pairs = scratch;        // nbk*cap dwords (~8.4MB), dead after bucket_build
    unsigned* h2    = scratch;        // N*16 dwords (6.4MB) bf16x2, written after pairs dead

    const int B = 256;
    const int PB = (E + EPB - 1) / EPB;

    hipMemsetAsync(gcursor, 0, MAXB * sizeof(int), stream);
    k_partition<<<PB + 4, B, 0, stream>>>(esrc, edst, gcursor, pairs, E, nbk, cap, PB, W1, wsW);
    k_bucket_build<<<nbk, B, 0, stream>>>(pairs, gcursor, rowptr, col, dis, cap, N);

    k_mm1<<<(N + 63) / 64, B, 0, stream>>>(x, wsW, h1, N);

    // fused layer-1 aggregation + layer-2 transform (1 row per wave-iter, ~8 rows/wave)
    const int fblocks = (N + 31) / 32;
    k_agg64_mm2<<<fblocks, B, 0, stream>>>((const unsigned*)h1, rowptr, col, dis, b1, W2, h2, N);

    // final aggregation: 1 row per wave
    k_agg32<<<(int)(((long long)N * 64 + B - 1) / B), B, 0, stream>>>((const unsigned*)h2, rowptr, col, dis, b2, out, N);
}

// Round 10
// 247.176 us; speedup vs baseline: 1.0357x; 1.0081x over previous
//
#include <hip/hip_runtime.h>
#include <hip/hip_bf16.h>

#define IN_CH 128
#define HID_CH 64
#define OUT_CH 32
#define EPB 2048  // edges per partition block
#define MAXB 512  // max buckets (N <= 131072)

typedef unsigned short ushort_t;
typedef __attribute__((ext_vector_type(8))) short short8;
typedef __attribute__((ext_vector_type(4))) float float4v;

static __device__ __forceinline__ ushort_t f2bf(float f) {
    unsigned u = __float_as_uint(f);
    unsigned r = (u + 0x7fff + ((u >> 16) & 1)) >> 16;  // RNE
    return (ushort_t)r;
}
static __device__ __forceinline__ float bf_lo(unsigned u) { return __uint_as_float(u << 16); }
static __device__ __forceinline__ float bf_hi(unsigned u) { return __uint_as_float(u & 0xffff0000u); }

// ---------------- radix partition by dst>>8 (+ prepW in 4 trailing blocks) ----------------

__global__ __launch_bounds__(256) void k_partition(const int* __restrict__ src,
                                                   const int* __restrict__ dst,
                                                   int* __restrict__ gcursor,
                                                   unsigned* __restrict__ pairs,
                                                   int E, int nbk, int cap, int PB,
                                                   const float* __restrict__ W1,
                                                   unsigned* __restrict__ wsW) {
    __shared__ int lhist[MAXB];
    __shared__ int lbase[MAXB];
    __shared__ int lcur[MAXB];
    const int tid = threadIdx.x;

    if (blockIdx.x >= PB) {  // prepW blocks: W1 -> b-fragment repack (bf16)
        int s = (blockIdx.x - PB) * 256 + tid;  // 0..1023
        int lane = s & 63;
        int nt = (s >> 6) & 3;
        int kc = s >> 8;
        int c = nt * 16 + (lane & 15);
        int k0 = kc * 32 + (lane >> 4) * 8;
        unsigned o[4];
#pragma unroll
        for (int d = 0; d < 4; ++d) {
            unsigned lo = f2bf(W1[(k0 + 2 * d) * 64 + c]);
            unsigned hi = f2bf(W1[(k0 + 2 * d + 1) * 64 + c]);
            o[d] = lo | (hi << 16);
        }
        ((uint4*)wsW)[s] = make_uint4(o[0], o[1], o[2], o[3]);
        return;
    }

    for (int b = tid; b < nbk; b += 256) { lhist[b] = 0; lcur[b] = 0; }
    __syncthreads();
    int s[8], d[8];
    const int e0 = blockIdx.x * EPB;
#pragma unroll
    for (int j = 0; j < 8; ++j) {
        int e = e0 + j * 256 + tid;
        if (e < E) {
            s[j] = src[e];
            d[j] = dst[e];
            atomicAdd(&lhist[d[j] >> 8], 1);
        } else {
            d[j] = -1;
        }
    }
    __syncthreads();
    for (int b = tid; b < nbk; b += 256)
        lbase[b] = lhist[b] ? atomicAdd(&gcursor[b], lhist[b]) : 0;
    __syncthreads();
#pragma unroll
    for (int j = 0; j < 8; ++j) {
        if (d[j] >= 0) {
            int b = d[j] >> 8;
            int loc = atomicAdd(&lcur[b], 1);
            int idx = lbase[b] + loc;
            if (idx < cap)
                pairs[(long long)b * cap + idx] = ((unsigned)s[j] << 8) | (unsigned)(d[j] & 255);
        }
    }
}

// ---------------- fused per-bucket build (inline bucket-total scan) ----------------
// Also zeroes the h1 pad row (index N) used by gather pad lanes.

__global__ __launch_bounds__(256) void k_bucket_build(const unsigned* __restrict__ pairs,
                                                      const int* __restrict__ gcursor,
                                                      int* __restrict__ rowptr,
                                                      int* __restrict__ col,
                                                      float* __restrict__ dis,
                                                      unsigned* __restrict__ h1zero,
                                                      int cap, int N) {
    __shared__ int lc[256];
    __shared__ int ls[256];
    __shared__ int lcur[256];
    const int b = blockIdx.x, tid = threadIdx.x;

    if (b == 0 && tid < 32) h1zero[tid] = 0;  // h1 pad row (64 bf16 = 32 dwords)

    // inline exclusive-scan of bucket totals (pairs of entries per thread)
    int ga = min(gcursor[2 * tid], cap);
    int gb = min(gcursor[2 * tid + 1], cap);
    ls[tid] = ga + gb;
    __syncthreads();
    for (int off = 1; off < 256; off <<= 1) {
        int val = (tid >= off) ? ls[tid - off] : 0;
        __syncthreads();
        ls[tid] += val;
        __syncthreads();
    }
    const int p = b >> 1;
    const int base = (p ? ls[p - 1] : 0) + ((b & 1) ? min(gcursor[b - 1], cap) : 0);
    const int total = ls[255];
    __syncthreads();
    if (b == 0 && tid == 0) rowptr[N] = total;

    lc[tid] = 0;
    __syncthreads();
    const int cnt = min(gcursor[b], cap);
    const unsigned* pp = pairs + (long long)b * cap;
    for (int i = tid; i < cnt; i += 256) atomicAdd(&lc[pp[i] & 255], 1);
    __syncthreads();
    const int v = lc[tid];
    ls[tid] = v;
    __syncthreads();
    for (int off = 1; off < 256; off <<= 1) {
        int val = (tid >= off) ? ls[tid - off] : 0;
        __syncthreads();
        ls[tid] += val;
        __syncthreads();
    }
    const int excl = ls[tid] - v;
    const int row = b * 256 + tid;
    if (row < N) {
        rowptr[row] = base + excl;
        dis[row] = rsqrtf((float)(v + 1));  // +1 self-loop
    }
    lcur[tid] = base + excl;
    __syncthreads();
    for (int i = tid; i < cnt; i += 256) {
        unsigned pk = pp[i];
        int pos = atomicAdd(&lcur[pk & 255], 1);
        col[pos] = (int)(pk >> 8);
    }
}

// ---------------- L1 matmul via MFMA; output pre-scaled: h1' = dis[row]*(x@W1) ----------------
// Also zeroes the h2 pad row (h2 region is dead 'pairs' scratch at this point).

__global__ __launch_bounds__(256) void k_mm1(const float* __restrict__ X,
                                             const unsigned* __restrict__ wsW,
                                             const float* __restrict__ dis,
                                             ushort_t* __restrict__ H,
                                             unsigned* __restrict__ h2zero, int N) {
    const int tid = threadIdx.x;
    if (blockIdx.x == 0 && tid < 16) h2zero[tid] = 0;  // h2 pad row (32 bf16 = 16 dwords)

    const int wv = tid >> 6, lane = tid & 63;
    const int quad = lane >> 4, n16 = lane & 15;
    const int rowbase = blockIdx.x * 64 + wv * 16;
    const int myrow = rowbase + n16;
    const bool rok = (myrow < N);

    float4v acc0 = {}, acc1 = {}, acc2 = {}, acc3 = {};

#pragma unroll
    for (int kc = 0; kc < 4; ++kc) {
        float4 xa = make_float4(0.f, 0.f, 0.f, 0.f), xb = xa;
        if (rok) {
            const float4* p = (const float4*)(X + (long long)myrow * 128 + kc * 32 + quad * 8);
            xa = p[0];
            xb = p[1];
        }
        unsigned pk[4];
        pk[0] = (unsigned)f2bf(xa.x) | ((unsigned)f2bf(xa.y) << 16);
        pk[1] = (unsigned)f2bf(xa.z) | ((unsigned)f2bf(xa.w) << 16);
        pk[2] = (unsigned)f2bf(xb.x) | ((unsigned)f2bf(xb.y) << 16);
        pk[3] = (unsigned)f2bf(xb.z) | ((unsigned)f2bf(xb.w) << 16);
        short8 a;
        a[0] = (short)(pk[0] & 0xffff); a[1] = (short)(pk[0] >> 16);
        a[2] = (short)(pk[1] & 0xffff); a[3] = (short)(pk[1] >> 16);
        a[4] = (short)(pk[2] & 0xffff); a[5] = (short)(pk[2] >> 16);
        a[6] = (short)(pk[3] & 0xffff); a[7] = (short)(pk[3] >> 16);

        const short8* wb = (const short8*)wsW;
        short8 b0 = wb[(kc * 4 + 0) * 64 + lane];
        short8 b1 = wb[(kc * 4 + 1) * 64 + lane];
        short8 b2 = wb[(kc * 4 + 2) * 64 + lane];
        short8 b3 = wb[(kc * 4 + 3) * 64 + lane];

        acc0 = __builtin_amdgcn_mfma_f32_16x16x32_bf16(a, b0, acc0, 0, 0, 0);
        acc1 = __builtin_amdgcn_mfma_f32_16x16x32_bf16(a, b1, acc1, 0, 0, 0);
        acc2 = __builtin_amdgcn_mfma_f32_16x16x32_bf16(a, b2, acc2, 0, 0, 0);
        acc3 = __builtin_amdgcn_mfma_f32_16x16x32_bf16(a, b3, acc3, 0, 0, 0);
    }

#pragma unroll
    for (int i = 0; i < 4; ++i) {
        int row = rowbase + quad * 4 + i;
        if (row < N) {
            float dr = dis[row];
            long long o = (long long)row * 64 + n16;
            H[o]      = f2bf(dr * acc0[i]);
            H[o + 16] = f2bf(dr * acc1[i]);
            H[o + 32] = f2bf(dr * acc2[i]);
            H[o + 48] = f2bf(dr * acc3[i]);
        }
    }
}

// ---------------- fused agg64 + mm2: pre-scaled pure-sum gather ----------------
// z = b1 + dr*(sum_{nbrs} h1'_s + h1'_row); h2' = dr * (relu(z) @ W2), stored bf16.
// Pad lanes point at zero row N. 16-lane edge groups, 8 uint2 in flight per lane.

__global__ __launch_bounds__(256) void k_agg64_mm2(const unsigned* __restrict__ h,
                                                   const int* __restrict__ rowptr,
                                                   const int* __restrict__ col,
                                                   const float* __restrict__ dis,
                                                   const float* __restrict__ b1,
                                                   const float* __restrict__ W2,
                                                   unsigned* __restrict__ h2, int N) {
    __shared__ float zbuf[4][64];
    __shared__ float sW2[64 * 32];  // 8 KB
    const int tid = threadIdx.x;
    for (int i = tid; i < 512; i += 256) ((float4*)sW2)[i] = ((const float4*)W2)[i];
    __syncthreads();

    const int wv = tid >> 6, lane = tid & 63;
    const int t = lane & 15, g = lane >> 4;      // gather mapping
    const int c32 = lane & 31, kh = lane >> 5;   // dot mapping: out-ch c32, k-half kh
    const float4 bq = ((const float4*)b1)[t];    // b1 channels 4t..4t+3

    const int wave0 = blockIdx.x * 4 + wv;
    const int nwaves = gridDim.x * 4;
    const uint2* h2w = (const uint2*)h;

    for (int row = wave0; row < N; row += nwaves) {
        const int start = rowptr[row];
        const int deg = rowptr[row + 1] - start;
        const float dr = dis[row];

        int myCol = N;  // pad -> zero row
        if (lane < deg) myCol = col[start + lane];

        uint2 us = h2w[row * 16 + t];  // self-loop (group 0 only)
        float a0 = 0.f, a1 = 0.f, a2 = 0.f, a3 = 0.f;
        if (g == 0) {
            a0 = bf_lo(us.x); a1 = bf_hi(us.x);
            a2 = bf_lo(us.y); a3 = bf_hi(us.y);
        }

        const int cnt = min(deg, 64);
        for (int k0 = 0; k0 < cnt; k0 += 32) {  // 32 edges per iter, 8 uint2/lane in flight
#pragma unroll
            for (int u = 0; u < 8; ++u) {
                int slot = k0 + 4 * u + g;
                int s = __shfl(myCol, slot);
                uint2 uu = h2w[s * 16 + t];
                a0 += bf_lo(uu.x); a1 += bf_hi(uu.x);
                a2 += bf_lo(uu.y); a3 += bf_hi(uu.y);
            }
        }
        for (int j = start + 64 + g; j < start + deg; j += 4) {  // rare tail
            int s = col[j];
            uint2 uu = h2w[s * 16 + t];
            a0 += bf_lo(uu.x); a1 += bf_hi(uu.x);
            a2 += bf_lo(uu.y); a3 += bf_hi(uu.y);
        }
        a0 += __shfl_down(a0, 32); a1 += __shfl_down(a1, 32);
        a2 += __shfl_down(a2, 32); a3 += __shfl_down(a3, 32);
        a0 += __shfl_down(a0, 16); a1 += __shfl_down(a1, 16);
        a2 += __shfl_down(a2, 16); a3 += __shfl_down(a3, 16);

        if (lane < 16) {  // lanes 0..15 hold channels 4t..4t+3 totals
            float4 zq;
            zq.x = bq.x + dr * a0;
            zq.y = bq.y + dr * a1;
            zq.z = bq.z + dr * a2;
            zq.w = bq.w + dr * a3;
            *(float4*)&zbuf[wv][4 * t] = zq;
        }
        __builtin_amdgcn_wave_barrier();

        // dot: lane (c32, kh) -> partial over k in [kh*32, kh*32+32)
        float acc = 0.f;
        const float* zp = &zbuf[wv][kh * 32];
        const float* wp = &sW2[kh * 32 * 32 + c32];
#pragma unroll
        for (int k = 0; k < 32; k += 4) {
            float4 zv = *(const float4*)(zp + k);
            acc += fmaxf(zv.x, 0.f) * wp[k * 32] + fmaxf(zv.y, 0.f) * wp[(k + 1) * 32] +
                   fmaxf(zv.z, 0.f) * wp[(k + 2) * 32] + fmaxf(zv.w, 0.f) * wp[(k + 3) * 32];
        }
        __builtin_amdgcn_wave_barrier();
        acc += __shfl_down(acc, 32);  // lanes 0..31 hold out channel c32

        const int tt = lane & 15;
        float o0 = __shfl(acc, 2 * tt);
        float o1 = __shfl(acc, 2 * tt + 1);
        if (lane < 16)  // store pre-scaled h2' = dr * h2
            h2[row * 16 + tt] = (unsigned)f2bf(dr * o0) | ((unsigned)f2bf(dr * o1) << 16);
    }
}

// ---------------- agg32: pre-scaled pure-sum final aggregation (fp32 out) ----------------
// out = b2 + dr*(sum h2'_s + h2'_row). 8-lane edge groups, 8 uint2 in flight.

__global__ __launch_bounds__(256) void k_agg32(const unsigned* __restrict__ h,
                                               const int* __restrict__ rowptr,
                                               const int* __restrict__ col,
                                               const float* __restrict__ dis,
                                               const float* __restrict__ b,
                                               float* __restrict__ out, int N) {
    const int wave = (blockIdx.x * 256 + threadIdx.x) >> 6;
    const int lane = threadIdx.x & 63;
    if (wave >= N) return;
    const int row = wave;
    const int t = lane & 7, g = lane >> 3;

    const int start = rowptr[row];
    const int deg = rowptr[row + 1] - start;
    const float dr = dis[row];

    int myCol = N;  // pad -> zero row
    if (lane < deg) myCol = col[start + lane];

    const uint2* hw = (const uint2*)h;
    uint2 us = hw[row * 8 + t];
    float a0 = 0.f, a1 = 0.f, a2 = 0.f, a3 = 0.f;
    if (g == 0) {
        a0 = bf_lo(us.x); a1 = bf_hi(us.x);
        a2 = bf_lo(us.y); a3 = bf_hi(us.y);
    }

    const int cnt = min(deg, 64);
    for (int k0 = 0; k0 < cnt; k0 += 64) {  // 64 edges per iter, 8 uint2/lane in flight
#pragma unroll
        for (int u = 0; u < 8; ++u) {
            int slot = k0 + 8 * u + g;
            int s = __shfl(myCol, slot);
            uint2 uu = hw[s * 8 + t];
            a0 += bf_lo(uu.x); a1 += bf_hi(uu.x);
            a2 += bf_lo(uu.y); a3 += bf_hi(uu.y);
        }
    }
    for (int j = start + 64 + g; j < start + deg; j += 8) {  // rare tail
        int s = col[j];
        uint2 uu = hw[s * 8 + t];
        a0 += bf_lo(uu.x); a1 += bf_hi(uu.x);
        a2 += bf_lo(uu.y); a3 += bf_hi(uu.y);
    }
    a0 += __shfl_down(a0, 32); a1 += __shfl_down(a1, 32);
    a2 += __shfl_down(a2, 32); a3 += __shfl_down(a3, 32);
    a0 += __shfl_down(a0, 16); a1 += __shfl_down(a1, 16);
    a2 += __shfl_down(a2, 16); a3 += __shfl_down(a3, 16);
    a0 += __shfl_down(a0, 8);  a1 += __shfl_down(a1, 8);
    a2 += __shfl_down(a2, 8);  a3 += __shfl_down(a3, 8);

    if (lane < 8) {  // lanes 0..7 hold channels 4t..4t+3
        float4 bq = ((const float4*)b)[t];
        float4 o;
        o.x = bq.x + dr * a0;
        o.y = bq.y + dr * a1;
        o.z = bq.z + dr * a2;
        o.w = bq.w + dr * a3;
        ((float4*)out)[(long long)row * 8 + t] = o;
    }
}

extern "C" void kernel_launch(void* const* d_in, const int* in_sizes, int n_in,
                              void* d_out, int out_size, void* d_ws, size_t ws_size,
                              hipStream_t stream) {
    const float* x  = (const float*)d_in[0];
    const int*   ei = (const int*)d_in[1];
    const float* W1 = (const float*)d_in[2];
    const float* b1 = (const float*)d_in[3];
    const float* W2 = (const float*)d_in[4];
    const float* b2 = (const float*)d_in[5];
    float* out = (float*)d_out;

    const int N = in_sizes[0] / IN_CH;
    const int E = in_sizes[1] / 2;
    const int* esrc = ei;
    const int* edst = ei + E;

    int nbk = (N + 255) >> 8;
    if (nbk > MAXB) nbk = MAXB;
    const int per_b = (E + nbk - 1) / nbk;
    const int cap = per_b + per_b / 4 + 256;  // ~20-sigma headroom

    // workspace layout (4-byte units, regions padded to 16); h1/h2 have pad row N
    int* rowptr   = (int*)d_ws;                          // N+1
    int* gcursor  = rowptr + (((N + 1) + 15) & ~15);     // MAXB
    unsigned* wsW = (unsigned*)(gcursor + MAXB);         // 4096 dwords (b-frag repack)
    int* col      = (int*)(wsW + 4096);                  // E
    float* dis    = (float*)(col + ((E + 15) & ~15));    // N
    ushort_t* h1  = (ushort_t*)(dis + ((N + 15) & ~15)); // (N+1)*64 bf16
    unsigned* scratch = (unsigned*)(h1 + (((long long)(N + 1) * 64 + 31) & ~31LL));
    unsigned* pairs = scratch;        // nbk*cap dwords (~8.4MB), dead after bucket_build
    unsigned* h2    = scratch;        // (N+1)*16 dwords bf16x2, written after pairs dead

    const int B = 256;
    const int PB = (E + EPB - 1) / EPB;

    hipMemsetAsync(gcursor, 0, MAXB * sizeof(int), stream);
    k_partition<<<PB + 4, B, 0, stream>>>(esrc, edst, gcursor, pairs, E, nbk, cap, PB, W1, wsW);
    k_bucket_build<<<nbk, B, 0, stream>>>(pairs, gcursor, rowptr, col, dis,
                                          (unsigned*)(h1 + (long long)N * 64), cap, N);

    k_mm1<<<(N + 63) / 64, B, 0, stream>>>(x, wsW, dis, h1, h2 + (long long)N * 16, N);

    // fused layer-1 aggregation + layer-2 transform (1 row per wave-iter, ~8 rows/wave)
    const int fblocks = (N + 31) / 32;
    k_agg64_mm2<<<fblocks, B, 0, stream>>>((const unsigned*)h1, rowptr, col, dis, b1, W2, h2, N);

    // final aggregation: 1 row per wave
    k_agg32<<<(int)(((long long)N * 64 + B - 1) / B), B, 0, stream>>>((const unsigned*)h2, rowptr, col, dis, b2, out, N);
}